// Round 1
// baseline (438.929 us; speedup 1.0000x reference)
//
#include <hip/hip_runtime.h>

// Problem constants
#define P_TOTAL 132096
#define NPOOL   4096
#define GDIM    1000
#define HDIM    150
#define MGRP    2048
#define KMAX    128

typedef __attribute__((ext_vector_type(4))) float f32x4;
typedef __attribute__((ext_vector_type(8))) short short8;

// ---------- workspace layout (bytes) ----------
// W1cT : bf16 [32][160][32]          327,680 B   @ 0
// W1abT: bf16 [32][320][32]          655,360 B   @ 327,680
// W2T  : bf16 [5][160][32]            51,200 B   @ 983,040
// ABpre: f32  [4096][320]          5,242,880 B   @ 1,034,240
// tabs : f32  [20][160]               12,800 B   @ 6,277,120
// sgrid: f32  [2048][128]          1,048,576 B   @ 6,289,920
// total: 7,338,496 B
#define OFF_W1CT   0
#define OFF_W1ABT  327680
#define OFF_W2T    983040
#define OFF_ABPRE  1034240
#define OFF_TABS   6277120
#define OFF_SGRID  6289920

__device__ __forceinline__ short f2bf(float f) {
  union { float f; unsigned u; } v; v.f = f;
  unsigned r = v.u + 0x7FFFu + ((v.u >> 16) & 1u);   // RNE
  return (short)(r >> 16);
}

__device__ __forceinline__ short8 pack8(f32x4 a, f32x4 b) {
  short8 r;
  r[0]=f2bf(a[0]); r[1]=f2bf(a[1]); r[2]=f2bf(a[2]); r[3]=f2bf(a[3]);
  r[4]=f2bf(b[0]); r[5]=f2bf(b[1]); r[6]=f2bf(b[2]); r[7]=f2bf(b[3]);
  return r;
}

// ---------- kernel 1: pack weights to bf16, transposed-chunked [c][n][kk] ----------
__global__ __launch_bounds__(256) void pack_kernel(const float* __restrict__ W1,
                                                   const float* __restrict__ W2,
                                                   short* __restrict__ w1ct,
                                                   short* __restrict__ w1abt,
                                                   short* __restrict__ w2t) {
  int idx = blockIdx.x * 256 + threadIdx.x;
  const int T1 = 32*160*32, T2 = 32*320*32, T3 = 5*160*32;
  if (idx < T1) {                               // W1c rows 2000..2999 -> [32][160][32]
    int c = idx / (160*32); int rem = idx % (160*32);
    int n = rem / 32, kk = rem % 32;
    int k = c*32 + kk;
    float v = (k < GDIM && n < HDIM) ? W1[(2000 + k)*HDIM + n] : 0.f;
    w1ct[idx] = f2bf(v);
  } else if (idx < T1 + T2) {                   // [W1a | W1b] -> [32][320][32]
    int i = idx - T1;
    int c = i / (320*32); int rem = i % (320*32);
    int n = rem / 32, kk = rem % 32;
    int k = c*32 + kk;
    float v = 0.f;
    if (k < GDIM) {
      if (n < HDIM)                 v = W1[k*HDIM + n];
      else if (n >= 160 && n < 310) v = W1[(1000 + k)*HDIM + (n - 160)];
    }
    w1abt[i] = f2bf(v);
  } else if (idx < T1 + T2 + T3) {              // W2 -> [5][160][32]
    int i = idx - T1 - T2;
    int c = i / (160*32); int rem = i % (160*32);
    int n = rem / 32, kk = rem % 32;
    int k = c*32 + kk;
    float v = (k < HDIM && n < HDIM) ? W2[k*HDIM + n] : 0.f;
    w2t[i] = f2bf(v);
  }
}

// ---------- kernel 2: phi projection tables (b1 folded into dist table) ----------
__global__ __launch_bounds__(256) void tables_kernel(const float* __restrict__ dist_emb,
                                                     const float* __restrict__ genre_emb,
                                                     const float* __restrict__ spk_emb,
                                                     const float* __restrict__ W1,
                                                     const float* __restrict__ b1,
                                                     float* __restrict__ tabs) {
  int idx = blockIdx.x * 256 + threadIdx.x;     // 20 rows x 160 cols
  if (idx >= 20*160) return;
  int row = idx / 160, n = idx % 160;
  float acc = 0.f;
  if (n < HDIM) {
    const float* emb; int woff;
    if (row < 9)       { emb = dist_emb  + row*20;      woff = 3000; acc = b1[n]; }
    else if (row < 17) { emb = genre_emb + (row-9)*20;  woff = 3020; }
    else               { emb = spk_emb   + (row-17)*20; woff = 3040; }
    #pragma unroll
    for (int kk = 0; kk < 20; ++kk) acc += emb[kk] * W1[(woff + kk)*HDIM + n];
  }
  tabs[idx] = acc;
}

// ---------- kernel 3: ABpre[4096][320] = g_i @ [W1a | W1b]  (bf16 MFMA) ----------
__global__ __launch_bounds__(256) void pre_gemm_kernel(const float* __restrict__ g_i,
                                                       const short* __restrict__ w1abt,
                                                       float* __restrict__ abpre) {
  int wave = threadIdx.x >> 6, lane = threadIdx.x & 63;
  int quad = lane >> 4, n16 = lane & 15;
  int rowbase = blockIdx.x * 64 + wave * 16;
  int colbase = blockIdx.y * 160;

  f32x4 acc[10];
  #pragma unroll
  for (int t = 0; t < 10; ++t) acc[t] = (f32x4){0.f, 0.f, 0.f, 0.f};

  const float* arow = g_i + (long)(rowbase + n16) * GDIM;

  for (int c = 0; c < 32; ++c) {
    int k = c*32 + quad*8;
    short8 a;
    if (k < GDIM) {
      f32x4 x0 = *(const f32x4*)(arow + k);
      f32x4 x1 = *(const f32x4*)(arow + k + 4);
      a = pack8(x0, x1);
    } else {
      a = (short8){0,0,0,0,0,0,0,0};
    }
    const short* bp = w1abt + ((c*320 + colbase + n16) * 32 + quad*8);
    #pragma unroll
    for (int t = 0; t < 10; ++t) {
      short8 b = *(const short8*)(bp + t*16*32);
      acc[t] = __builtin_amdgcn_mfma_f32_16x16x32_bf16(a, b, acc[t], 0, 0, 0);
    }
  }
  // C layout: col = lane&15, row = quad*4 + r
  #pragma unroll
  for (int t = 0; t < 10; ++t) {
    #pragma unroll
    for (int r = 0; r < 4; ++r) {
      int row = rowbase + quad*4 + r;
      abpre[(long)row * 320 + colbase + t*16 + n16] = acc[t][r];
    }
  }
}

// ---------- kernel 4: per-pair fused MLP + score scatter ----------
__global__ __launch_bounds__(256) void pair_kernel(
    const float* __restrict__ g_i, const float* __restrict__ ms,
    const short* __restrict__ w1ct, const short* __restrict__ w2t,
    const float* __restrict__ abpre, const float* __restrict__ tabs,
    const float* __restrict__ b2, const float* __restrict__ W3,
    const float* __restrict__ b3,
    const int* __restrict__ mention_ids, const int* __restrict__ antecedent_ids,
    const int* __restrict__ dist_ids, const int* __restrict__ genre_ids,
    const int* __restrict__ spk_ids, const int* __restrict__ seg_ids,
    const int* __restrict__ offs, float* __restrict__ sgrid) {

  __shared__ __align__(16) short h1s[4][16*176];   // stride 176 to spread banks

  int wave = threadIdx.x >> 6, lane = threadIdx.x & 63;
  int quad = lane >> 4, n16 = lane & 15;
  int p0 = blockIdx.x * 64 + wave * 16;

  // A-fragment row for this lane: pair m = n16
  int pm = p0 + n16;
  int a_mi = mention_ids[pm], a_ai = antecedent_ids[pm];
  const float* rm = g_i + (long)a_mi * GDIM;
  const float* ra = g_i + (long)a_ai * GDIM;

  f32x4 acc[10];
  #pragma unroll
  for (int t = 0; t < 10; ++t) acc[t] = (f32x4){0.f, 0.f, 0.f, 0.f};

  // ---- layer-1 product-term GEMM: [16 x 1024] x [1024 x 160] ----
  for (int c = 0; c < 32; ++c) {
    int k = c*32 + quad*8;
    short8 a;
    if (k < GDIM) {
      f32x4 m0 = *(const f32x4*)(rm + k);
      f32x4 m1 = *(const f32x4*)(rm + k + 4);
      f32x4 a0 = *(const f32x4*)(ra + k);
      f32x4 a1 = *(const f32x4*)(ra + k + 4);
      a = pack8(m0 * a0, m1 * a1);
    } else {
      a = (short8){0,0,0,0,0,0,0,0};
    }
    const short* bp = w1ct + ((c*160 + n16) * 32 + quad*8);
    #pragma unroll
    for (int t = 0; t < 10; ++t) {
      short8 b = *(const short8*)(bp + t*16*32);
      acc[t] = __builtin_amdgcn_mfma_f32_16x16x32_bf16(a, b, acc[t], 0, 0, 0);
    }
  }

  // ---- epilogue 1: add precomputed terms, relu, stash h1 (bf16) in LDS ----
  int idm[4], ida[4], idd[4], idg[4], idsp[4];
  #pragma unroll
  for (int r = 0; r < 4; ++r) {
    int pr = p0 + quad*4 + r;
    idm[r]  = mention_ids[pr];
    ida[r]  = antecedent_ids[pr];
    idd[r]  = dist_ids[pr];
    idg[r]  = genre_ids[pr];
    idsp[r] = spk_ids[pr];
  }
  const float* Dd = tabs;             // 9 x 160 (includes b1)
  const float* Ge = tabs + 9*160;     // 8 x 160
  const float* Se = tabs + 17*160;    // 3 x 160

  #pragma unroll
  for (int t = 0; t < 10; ++t) {
    int n = t*16 + n16;
    #pragma unroll
    for (int r = 0; r < 4; ++r) {
      float v = acc[t][r]
              + abpre[(long)idm[r]*320 + n]
              + abpre[(long)ida[r]*320 + 160 + n]
              + Dd[idd[r]*160 + n]
              + Ge[idg[r]*160 + n]
              + Se[idsp[r]*160 + n];
      v = fmaxf(v, 0.f);
      h1s[wave][(quad*4 + r)*176 + n] = f2bf(v);
    }
  }
  __syncthreads();

  // ---- layer 2: h2 = relu(h1 @ W2 + b2), K = 160 (5 chunks) ----
  f32x4 acc2[10];
  #pragma unroll
  for (int t = 0; t < 10; ++t) acc2[t] = (f32x4){0.f, 0.f, 0.f, 0.f};

  #pragma unroll
  for (int c = 0; c < 5; ++c) {
    short8 a = *(const short8*)(&h1s[wave][n16*176 + c*32 + quad*8]);
    const short* bp = w2t + ((c*160 + n16) * 32 + quad*8);
    #pragma unroll
    for (int t = 0; t < 10; ++t) {
      short8 b = *(const short8*)(bp + t*16*32);
      acc2[t] = __builtin_amdgcn_mfma_f32_16x16x32_bf16(a, b, acc2[t], 0, 0, 0);
    }
  }

  // ---- layer 3: s = h2 @ W3 + b3, in-register + quad-wide shuffle reduce ----
  float part[4] = {0.f, 0.f, 0.f, 0.f};
  #pragma unroll
  for (int t = 0; t < 10; ++t) {
    int n = t*16 + n16;
    float w3v = (n < HDIM) ? W3[n] : 0.f;
    float b2v = (n < HDIM) ? b2[n] : 0.f;
    #pragma unroll
    for (int r = 0; r < 4; ++r) {
      float h2 = fmaxf(acc2[t][r] + b2v, 0.f);
      part[r] += h2 * w3v;
    }
  }
  for (int msk = 1; msk < 16; msk <<= 1) {
    #pragma unroll
    for (int r = 0; r < 4; ++r) part[r] += __shfl_xor(part[r], msk);
  }

  if (n16 == 0) {
    float bias3 = b3[0];
    #pragma unroll
    for (int r = 0; r < 4; ++r) {
      int pr = p0 + quad*4 + r;
      float sc = part[r] + bias3 + ms[idm[r]] + ms[ida[r]];
      sgrid[seg_ids[pr] * KMAX + offs[pr]] = sc;
    }
  }
}

// ---------- kernel 5: per-group softmax (+epsilon) and full output fill ----------
__global__ __launch_bounds__(128) void softmax_kernel(const float* __restrict__ sgrid,
                                                      const int* __restrict__ lengths,
                                                      float* __restrict__ out) {
  int b = blockIdx.x, t = threadIdx.x;   // 128 threads
  if (b == 0) {
    out[t] = (t == 0) ? 1.0f : 1000.0f;
    if (t == 0) out[128] = 1000.0f;
    return;
  }
  int m = b - 1;
  int len = lengths[m];
  float s = (t < len) ? sgrid[m * KMAX + t] : -1e30f;

  __shared__ float redA[2];
  __shared__ float redB[2];

  float v = s;
  #pragma unroll
  for (int o = 32; o >= 1; o >>= 1) v = fmaxf(v, __shfl_xor(v, o));
  if ((t & 63) == 0) redA[t >> 6] = v;
  __syncthreads();
  float mx = fmaxf(fmaxf(redA[0], redA[1]), 0.0f);

  float e = (t < len) ? expf(s - mx) : 0.f;
  float sum = e;
  #pragma unroll
  for (int o = 32; o >= 1; o >>= 1) sum += __shfl_xor(sum, o);
  if ((t & 63) == 0) redB[t >> 6] = sum;
  __syncthreads();

  float eps_e = expf(-mx);
  float denom = redB[0] + redB[1] + eps_e;

  float* row = out + (long)(m + 1) * 129;
  float val;
  if (t < len)       val = e / denom;
  else if (t == len) val = eps_e / denom;
  else               val = 1000.0f;
  row[t] = val;
  if (t == 0) row[128] = (len == KMAX) ? (eps_e / denom) : 1000.0f;
}

extern "C" void kernel_launch(void* const* d_in, const int* in_sizes, int n_in,
                              void* d_out, int out_size, void* d_ws, size_t ws_size,
                              hipStream_t stream) {
  const float* g_i        = (const float*)d_in[0];
  const float* ms         = (const float*)d_in[1];
  const float* dist_emb   = (const float*)d_in[2];
  const float* genre_emb  = (const float*)d_in[3];
  const float* spk_emb    = (const float*)d_in[4];
  const float* W1         = (const float*)d_in[5];
  const float* b1         = (const float*)d_in[6];
  const float* W2         = (const float*)d_in[7];
  const float* b2         = (const float*)d_in[8];
  const float* W3         = (const float*)d_in[9];
  const float* b3         = (const float*)d_in[10];
  const int* mention_ids    = (const int*)d_in[11];
  const int* antecedent_ids = (const int*)d_in[12];
  const int* dist_ids       = (const int*)d_in[13];
  const int* genre_ids      = (const int*)d_in[14];
  const int* spk_ids        = (const int*)d_in[15];
  const int* lengths        = (const int*)d_in[16];
  const int* seg_ids        = (const int*)d_in[17];
  const int* offsets        = (const int*)d_in[18];

  char* ws = (char*)d_ws;
  short* w1ct  = (short*)(ws + OFF_W1CT);
  short* w1abt = (short*)(ws + OFF_W1ABT);
  short* w2t   = (short*)(ws + OFF_W2T);
  float* abpre = (float*)(ws + OFF_ABPRE);
  float* tabs  = (float*)(ws + OFF_TABS);
  float* sgrid = (float*)(ws + OFF_SGRID);

  const int packN = 32*160*32 + 32*320*32 + 5*160*32;   // 517,120 -> 2020 blocks
  pack_kernel<<<(packN + 255)/256, 256, 0, stream>>>(W1, W2, w1ct, w1abt, w2t);
  tables_kernel<<<(20*160 + 255)/256, 256, 0, stream>>>(dist_emb, genre_emb, spk_emb, W1, b1, tabs);
  dim3 gpre(NPOOL/64, 2);
  pre_gemm_kernel<<<gpre, 256, 0, stream>>>(g_i, w1abt, abpre);
  pair_kernel<<<P_TOTAL/64, 256, 0, stream>>>(g_i, ms, w1ct, w2t, abpre, tabs,
                                              b2, W3, b3,
                                              mention_ids, antecedent_ids,
                                              dist_ids, genre_ids, spk_ids,
                                              seg_ids, offsets, sgrid);
  softmax_kernel<<<MGRP + 1, 128, 0, stream>>>(sgrid, lengths, (float*)d_out);
}